// Round 11
// baseline (339.480 us; speedup 1.0000x reference)
//
#include <hip/hip_runtime.h>

typedef short short8 __attribute__((ext_vector_type(8)));
typedef float float4v __attribute__((ext_vector_type(4)));
typedef unsigned short u16;
typedef unsigned int u32;

#define T_LEN 4096
#define DDIM 512
#define BATCH 8
#define MROWS 32768
#define CH 32
#define NC 128   // T_LEN / CH

__device__ __forceinline__ u16 f2b(float x) {
    unsigned u = __float_as_uint(x);
    unsigned r = (u + 0x7FFFu + ((u >> 16) & 1u)) >> 16;
    return (u16)r;
}
__device__ __forceinline__ float b2f(u16 h) {
    return __uint_as_float((u32)h << 16);
}
__device__ __forceinline__ float sigm(float x) {
    return __builtin_amdgcn_rcpf(1.f + __builtin_amdgcn_exp2f(-1.44269504f * x));
}
__device__ __forceinline__ float tanh_fast(float x) {
    return 1.f - 2.f * __builtin_amdgcn_rcpf(1.f + __builtin_amdgcn_exp2f(2.88539008f * x));
}

__device__ __forceinline__ void gl2lds16(const u16* g, u16* l) {
    __builtin_amdgcn_global_load_lds(
        (const __attribute__((address_space(1))) void*)g,
        (__attribute__((address_space(3))) void*)l, 16, 0, 0);
}

// ---------------- converts ----------------
__global__ __launch_bounds__(256) void cvt_x(const float* __restrict__ x,
                                             u16* __restrict__ xb, size_t n) {
    size_t i = ((size_t)blockIdx.x * 256 + threadIdx.x) * 4;
    if (i < n) {
        float4v v = *(const float4v*)&x[i];
        ushort4 p;
        p.x = f2b(v[0]); p.y = f2b(v[1]); p.z = f2b(v[2]); p.w = f2b(v[3]);
        *(ushort4*)&xb[i] = p;
    }
}

// Wt[j][k] = W[e][k][h], j = e*512+h
__global__ __launch_bounds__(256) void cvt_wt(const float* __restrict__ W,
                                              u16* __restrict__ Wt, int N) {
    int idx = blockIdx.x * 256 + threadIdx.x;
    if (idx >= N * 512) return;
    int j = idx >> 9;
    int k = idx & 511;
    int e = j >> 9, h = j & 511;
    Wt[(size_t)j * 512 + k] = f2b(W[((size_t)e * 512 + k) * 512 + h]);
}

// ---------------- GEMM + activation epilogue ----------------
// R9 pipeline family, deeper wave tiles: 256x128 block, 4 waves (2x2),
// wave tile 128x64 (8x4 acc of 16x16x32), BK=32, triple-buffer + counted
// vmcnt(6) (6 loads/thread/tile, depth 2), R7 chunk swizzle (0 conflicts),
// R9 chunked XCD swizzle (FETCH 135->48MB).
// Rationale: halves block-K-steps per output FLOP (amortizes the measured
// ~770cyc/K-step sync overhead), cuts LDS-read 31->23 B/kFLOP and staging
// 1GB->786MB. LDS 72KB -> 2 blocks/CU; launch_bounds(256,2) caps VGPR<=256.
// MODE 1: N=1024: tanh -> o0(v) bf16 | sigmoid -> o1(f1) bf16
// MODE 2: N=2048: f2->o0, i->o1, o->o2 (sigm), z->o3 (tanh), all bf16
// MODE 3: N=512 : raw + bias -> o0 (f32)
template <int MODE>
__global__ __launch_bounds__(256, 2) void gemm_act(
    const u16* __restrict__ A, const u16* __restrict__ Bt,
    const float* __restrict__ bias, void* __restrict__ o0v,
    void* __restrict__ o1v, void* __restrict__ o2v, void* __restrict__ o3v) {
    constexpr int K = 512;
    constexpr int BK = 32;             // K-step (u16), 64B rows
    constexpr int NKT = K / BK;        // 16
    constexpr int LBA = 256 * 32;      // A: 16KB per buffer
    constexpr int LBB = 128 * 32;      // B: 8KB per buffer
    constexpr int GX = (MODE == 1) ? 8 : (MODE == 2) ? 16 : 4;
    constexpr int NWG = 128 * GX;
    __shared__ u16 lsA[3][LBA];        // 48KB
    __shared__ u16 lsB[3][LBB];        // 24KB
    const int tid = threadIdx.x;
    const int lane = tid & 63;
    const int wid = tid >> 6;          // 0..3
    const int wr = wid >> 1;           // 0..1 (M: 128-row half)
    const int wc = wid & 1;            // 0..1 (N: 64-col half)
    const int l0 = lane & 15, lh = lane >> 4;

    // chunked XCD swizzle (bijective: NWG % 8 == 0)
    const int h = blockIdx.x;
    const int l = (h & 7) * (NWG / 8) + (h >> 3);
    const int bn0 = (l & (GX - 1)) * 128;
    const int bm0 = (l / GX) * 256;

    float4v acc[8][4];
#pragma unroll
    for (int m = 0; m < 8; ++m)
#pragma unroll
        for (int n = 0; n < 4; ++n) acc[m][n] = (float4v){0.f, 0.f, 0.f, 0.f};

    // staging: A 4 instrs (1024 slots), B 2 instrs (512 slots)
    // slot flat: row r = flat>>2 (4 chunks/row), cc = flat&3;
    // source chunk = cc ^ ((r>>1)&3) within the row's 64B span (coalesced)
    int growA[4], gchA[4], growB[2], gchB[2];
#pragma unroll
    for (int i = 0; i < 4; ++i) {
        int flat = i * 256 + tid;
        growA[i] = flat >> 2;
        gchA[i] = (((flat & 3) ^ ((growA[i] >> 1) & 3))) * 8;
    }
#pragma unroll
    for (int i = 0; i < 2; ++i) {
        int flat = i * 256 + tid;
        growB[i] = flat >> 2;
        gchB[i] = (((flat & 3) ^ ((growB[i] >> 1) & 3))) * 8;
    }

#define STAGE(buf, kt)                                                        \
    {                                                                         \
        const int k0 = (kt) * BK;                                             \
        _Pragma("unroll") for (int i = 0; i < 4; ++i)                         \
            gl2lds16(&A[(size_t)(bm0 + growA[i]) * K + k0 + gchA[i]],         \
                     &lsA[buf][(i * 256 + tid) * 8]);                         \
        _Pragma("unroll") for (int i = 0; i < 2; ++i)                         \
            gl2lds16(&Bt[(size_t)(bn0 + growB[i]) * K + k0 + gchB[i]],        \
                     &lsB[buf][(i * 256 + tid) * 8]);                         \
    }

    // prologue: 2 tiles in flight (12 loads/thread outstanding)
    STAGE(0, 0);
    STAGE(1, 1);

    for (int kt = 0; kt < NKT; ++kt) {
        const int cur = kt % 3;
        // wait only for the OLDEST tile's 6 loads; keep the next 6 in flight
        if (kt + 1 < NKT)
            asm volatile("s_waitcnt vmcnt(6)" ::: "memory");
        else
            asm volatile("s_waitcnt vmcnt(0)" ::: "memory");
        __builtin_amdgcn_s_barrier();
        __builtin_amdgcn_sched_barrier(0);
        // prefetch tile kt+2 into the buffer last read at iter kt-1 (safe:
        // those reads completed at iter kt-1's lgkmcnt(0), before barrier kt)
        if (kt + 2 < NKT) STAGE((kt + 2) % 3, kt + 2);
        short8 af[8], bf[4];
#pragma unroll
        for (int m = 0; m < 8; ++m) {
            int r = wr * 128 + m * 16 + l0;
            af[m] = *(const short8*)&lsA[cur][r * 32 + ((lh ^ ((r >> 1) & 3)) * 8)];
        }
#pragma unroll
        for (int n = 0; n < 4; ++n) {
            int r = wc * 64 + n * 16 + l0;
            bf[n] = *(const short8*)&lsB[cur][r * 32 + ((lh ^ ((r >> 1) & 3)) * 8)];
        }
        asm volatile("s_waitcnt lgkmcnt(0)" ::: "memory");
        __builtin_amdgcn_sched_barrier(0);
        __builtin_amdgcn_s_setprio(1);
#pragma unroll
        for (int m = 0; m < 8; ++m)
#pragma unroll
            for (int n = 0; n < 4; ++n)
                acc[m][n] = __builtin_amdgcn_mfma_f32_16x16x32_bf16(
                    af[m], bf[n], acc[m][n], 0, 0, 0);
        __builtin_amdgcn_s_setprio(0);
    }
#undef STAGE

#pragma unroll
    for (int m = 0; m < 8; ++m) {
#pragma unroll
        for (int n = 0; n < 4; ++n) {
            int col = bn0 + wc * 64 + n * 16 + l0;
            float bv = bias[col];
#pragma unroll
            for (int r = 0; r < 4; ++r) {
                int rw = bm0 + wr * 128 + m * 16 + lh * 4 + r;
                float u = acc[m][n][r] + bv;
                size_t oidx = (size_t)rw * 512 + (col & 511);
                if (MODE == 1) {
                    if (col < 512)
                        ((u16*)o0v)[oidx] = f2b(tanh_fast(u));
                    else
                        ((u16*)o1v)[oidx] = f2b(sigm(u));
                } else if (MODE == 2) {
                    int e = col >> 9;
                    if (e == 0)
                        ((u16*)o0v)[oidx] = f2b(sigm(u));
                    else if (e == 1)
                        ((u16*)o1v)[oidx] = f2b(sigm(u));
                    else if (e == 2)
                        ((u16*)o2v)[oidx] = f2b(sigm(u));
                    else
                        ((u16*)o3v)[oidx] = f2b(tanh_fast(u));
                } else {
                    ((float*)o0v)[oidx] = u;
                }
            }
        }
    }
}

// ---------------- chunked scan (bf16 streams, f32 state) ----------------
template <int S>
__global__ __launch_bounds__(128) void scan_p1(const u16* __restrict__ f,
                                               const u16* __restrict__ v,
                                               const u16* __restrict__ z,
                                               float* __restrict__ cA,
                                               float* __restrict__ cB) {
    int d0 = threadIdx.x * 4;
    int c = blockIdx.x & (NC - 1);
    int b = blockIdx.x >> 7;
    size_t base = ((size_t)b * T_LEN + c * CH) * DDIM + d0;
    float Aa[4] = {1.f, 1.f, 1.f, 1.f}, Bb[4] = {0.f, 0.f, 0.f, 0.f};
    for (int t = 0; t < CH; ++t) {
        ushort4 fq = *(const ushort4*)&f[base];
        ushort4 vq = *(const ushort4*)&v[base];
        float ff[4] = {b2f(fq.x), b2f(fq.y), b2f(fq.z), b2f(fq.w)};
        float gg[4] = {b2f(vq.x), b2f(vq.y), b2f(vq.z), b2f(vq.w)};
        if (S == 2) {
            ushort4 zq = *(const ushort4*)&z[base];
            gg[0] *= b2f(zq.x); gg[1] *= b2f(zq.y);
            gg[2] *= b2f(zq.z); gg[3] *= b2f(zq.w);
        }
#pragma unroll
        for (int j = 0; j < 4; ++j) {
            float g = (1.f - ff[j]) * gg[j];
            Bb[j] = ff[j] * Bb[j] + g;
            Aa[j] *= ff[j];
        }
        base += DDIM;
    }
    size_t ci = (size_t)c * 4096 + b * DDIM + d0;
#pragma unroll
    for (int j = 0; j < 4; ++j) {
        cA[ci + j] = Aa[j];
        cB[ci + j] = Bb[j];
    }
}

__global__ __launch_bounds__(256) void scan_p2(float* __restrict__ cA,
                                               const float* __restrict__ cB) {
    int ln = blockIdx.x * 256 + threadIdx.x;  // 0..4095 = b*512+d
    float h = 0.f;
    for (int c = 0; c < NC; ++c) {
        size_t ix = (size_t)c * 4096 + ln;
        float a = cA[ix], bb = cB[ix];
        cA[ix] = h;  // exclusive carry-in
        h = a * h + bb;
    }
}

template <int S>
__global__ __launch_bounds__(128) void scan_p3(
    const u16* __restrict__ f, const u16* __restrict__ v,
    const u16* __restrict__ z, const u16* __restrict__ o,
    const float* __restrict__ cA, u16* __restrict__ hb,
    float* __restrict__ hid) {
    int d0 = threadIdx.x * 4;
    int c = blockIdx.x & (NC - 1);
    int b = blockIdx.x >> 7;
    size_t base = ((size_t)b * T_LEN + c * CH) * DDIM + d0;
    size_t ci = (size_t)c * 4096 + b * DDIM + d0;
    float h[4] = {cA[ci], cA[ci + 1], cA[ci + 2], cA[ci + 3]};
    for (int t = 0; t < CH; ++t) {
        ushort4 fq = *(const ushort4*)&f[base];
        ushort4 vq = *(const ushort4*)&v[base];
        float ff[4] = {b2f(fq.x), b2f(fq.y), b2f(fq.z), b2f(fq.w)};
        float gg[4] = {b2f(vq.x), b2f(vq.y), b2f(vq.z), b2f(vq.w)};
        if (S == 2) {
            ushort4 zq = *(const ushort4*)&z[base];
            gg[0] *= b2f(zq.x); gg[1] *= b2f(zq.y);
            gg[2] *= b2f(zq.z); gg[3] *= b2f(zq.w);
        }
        float w[4];
#pragma unroll
        for (int j = 0; j < 4; ++j) {
            float g = (1.f - ff[j]) * gg[j];
            h[j] = ff[j] * h[j] + g;
            w[j] = h[j];
        }
        if (S == 2) {
            ushort4 oq = *(const ushort4*)&o[base];
            w[0] *= b2f(oq.x); w[1] *= b2f(oq.y);
            w[2] *= b2f(oq.z); w[3] *= b2f(oq.w);
        }
        ushort4 p;
        p.x = f2b(w[0]); p.y = f2b(w[1]); p.z = f2b(w[2]); p.w = f2b(w[3]);
        *(ushort4*)&hb[base] = p;
        base += DDIM;
    }
    if (c == NC - 1) {
#pragma unroll
        for (int j = 0; j < 4; ++j)
            hid[b * 1024 + (S == 1 ? 0 : 512) + d0 + j] = h[j];
    }
}

// ---------------- launch ----------------
extern "C" void kernel_launch(void* const* d_in, const int* in_sizes, int n_in,
                              void* d_out, int out_size, void* d_ws,
                              size_t ws_size, hipStream_t stream) {
    const float* x = (const float*)d_in[0];
    const float* W_in = (const float*)d_in[1];
    const float* b_in = (const float*)d_in[2];
    const float* W_mid = (const float*)d_in[3];
    const float* b_mid = (const float*)d_in[4];
    const float* W_out = (const float*)d_in[5];
    const float* b_out = (const float*)d_in[6];
    float* out = (float*)d_out;
    char* ws = (char*)d_ws;

    const size_t MB = 1u << 20;
    const size_t MD = (size_t)MROWS * DDIM;  // 16.7M elems

    u16* wt_in = (u16*)(ws);              // 1 MB
    u16* wt_mid = (u16*)(ws + 1 * MB);    // 2 MB
    u16* wt_out = (u16*)(ws + 3 * MB);    // 0.5 MB
    u16* hb = (u16*)(ws + 4 * MB);        // 32 MB (xb -> h1 -> s)
    u16* S0 = (u16*)(ws + 36 * MB);       // 32 MB
    u16* S1 = (u16*)(ws + 68 * MB);       // 32 MB
    u16* S2 = (u16*)(ws + 100 * MB);      // 32 MB
    u16* S3 = (u16*)(ws + 132 * MB);      // 32 MB
    float* cA = (float*)(ws + 164 * MB);  // 2 MB
    float* cB = (float*)(ws + 166 * MB);  // 2 MB
    float* hid = out + MD;

    cvt_x<<<(int)(MD / 4 / 256), 256, 0, stream>>>(x, hb, MD);
    cvt_wt<<<(1024 * 512) / 256, 256, 0, stream>>>(W_in, wt_in, 1024);
    cvt_wt<<<(2048 * 512) / 256, 256, 0, stream>>>(W_mid, wt_mid, 2048);
    cvt_wt<<<(512 * 512) / 256, 256, 0, stream>>>(W_out, wt_out, 512);

    // GEMM1: v(S0)=tanh, f1(S1)=sigmoid   (128 Mblk x 8 Nblk = 1024)
    gemm_act<1><<<1024, 256, 0, stream>>>(hb, wt_in, b_in, S0, S1, nullptr,
                                          nullptr);
    // scan1: h1 = scan(f1, (1-f1)*v) -> hb bf16; hidden_pre
    scan_p1<1><<<1024, 128, 0, stream>>>(S1, S0, nullptr, cA, cB);
    scan_p2<<<16, 256, 0, stream>>>(cA, cB);
    scan_p3<1><<<1024, 128, 0, stream>>>(S1, S0, nullptr, nullptr, cA, hb, hid);

    // GEMM2: f2(S0), i(S1), o(S2), z(S3)  (128 x 16 = 2048)
    gemm_act<2><<<2048, 256, 0, stream>>>(hb, wt_mid, b_mid, S0, S1, S2, S3);
    // scan2: h2 = scan(f2, (1-f2)*i*z); s = h2*o -> hb bf16; hidden_middle
    scan_p1<2><<<1024, 128, 0, stream>>>(S0, S1, S3, cA, cB);
    scan_p2<<<16, 256, 0, stream>>>(cA, cB);
    scan_p3<2><<<1024, 128, 0, stream>>>(S0, S1, S3, S2, cA, hb, hid);

    // GEMM3: out = s@W_out + b_out (f32)  (128 x 4 = 512)
    gemm_act<3><<<512, 256, 0, stream>>>(hb, wt_out, b_out, out, nullptr,
                                         nullptr, nullptr);
}

// Round 12
// 292.661 us; speedup vs baseline: 1.1600x; 1.1600x over previous
//
#include <hip/hip_runtime.h>

typedef short short8 __attribute__((ext_vector_type(8)));
typedef float float4v __attribute__((ext_vector_type(4)));
typedef unsigned short u16;
typedef unsigned int u32;

#define T_LEN 4096
#define DDIM 512
#define BATCH 8
#define MROWS 32768
#define CH 32
#define NC 128   // T_LEN / CH

__device__ __forceinline__ u16 f2b(float x) {
    unsigned u = __float_as_uint(x);
    unsigned r = (u + 0x7FFFu + ((u >> 16) & 1u)) >> 16;
    return (u16)r;
}
__device__ __forceinline__ float b2f(u16 h) {
    return __uint_as_float((u32)h << 16);
}
__device__ __forceinline__ float sigm(float x) {
    return __builtin_amdgcn_rcpf(1.f + __builtin_amdgcn_exp2f(-1.44269504f * x));
}
__device__ __forceinline__ float tanh_fast(float x) {
    return 1.f - 2.f * __builtin_amdgcn_rcpf(1.f + __builtin_amdgcn_exp2f(2.88539008f * x));
}

__device__ __forceinline__ void gl2lds16(const u16* g, u16* l) {
    __builtin_amdgcn_global_load_lds(
        (const __attribute__((address_space(1))) void*)g,
        (__attribute__((address_space(3))) void*)l, 16, 0, 0);
}

// ---------------- converts ----------------
__global__ __launch_bounds__(256) void cvt_x(const float* __restrict__ x,
                                             u16* __restrict__ xb, size_t n) {
    size_t i = ((size_t)blockIdx.x * 256 + threadIdx.x) * 4;
    if (i < n) {
        float4v v = *(const float4v*)&x[i];
        ushort4 p;
        p.x = f2b(v[0]); p.y = f2b(v[1]); p.z = f2b(v[2]); p.w = f2b(v[3]);
        *(ushort4*)&xb[i] = p;
    }
}

// Wt[j][k] = W[e][k][h], j = e*512+h
__global__ __launch_bounds__(256) void cvt_wt(const float* __restrict__ W,
                                              u16* __restrict__ Wt, int N) {
    int idx = blockIdx.x * 256 + threadIdx.x;
    if (idx >= N * 512) return;
    int j = idx >> 9;
    int k = idx & 511;
    int e = j >> 9, h = j & 511;
    Wt[(size_t)j * 512 + k] = f2b(W[((size_t)e * 512 + k) * 512 + h]);
}

// ---------------- GEMM + activation epilogue ----------------
// R9 per-wave shape (64x64 wave tile, 16 MFMA : 8 ds_read/step, BK=32,
// R7 chunk swizzle = 0 conflicts, counted vmcnt depth-2, XCD swizzle),
// repacked as 8 waves/block (BM=256 x BN=128, 512 threads):
//   LDS 72KB -> 2 blocks/CU = 16 waves/CU (R9: ~9.4). Waves/CU is the
//   empirically controlling variable (R5/R6/R9/R10/R11 series) -- inter-wave
//   overlap absorbs the per-K-step stage+barrier sync cost (m114).
// __launch_bounds__(512,4): 4 waves/EU = 2 blocks/CU, VGPR cap 128.
// MODE 1: N=1024: tanh -> o0(v) bf16 | sigmoid -> o1(f1) bf16
// MODE 2: N=2048: f2->o0, i->o1, o->o2 (sigm), z->o3 (tanh), all bf16
// MODE 3: N=512 : raw + bias -> o0 (f32)
template <int MODE>
__global__ __launch_bounds__(512, 4) void gemm_act(
    const u16* __restrict__ A, const u16* __restrict__ Bt,
    const float* __restrict__ bias, void* __restrict__ o0v,
    void* __restrict__ o1v, void* __restrict__ o2v, void* __restrict__ o3v) {
    constexpr int K = 512;
    constexpr int BK = 32;             // K-step (u16), 64B rows
    constexpr int NKT = K / BK;        // 16
    constexpr int LBA = 256 * 32;      // A: 16KB per buffer
    constexpr int LBB = 128 * 32;      // B: 8KB per buffer
    constexpr int GX = (MODE == 1) ? 8 : (MODE == 2) ? 16 : 4;
    constexpr int NWG = 128 * GX;
    __shared__ u16 lsA[3][LBA];        // 48KB
    __shared__ u16 lsB[3][LBB];        // 24KB
    const int tid = threadIdx.x;
    const int lane = tid & 63;
    const int wid = tid >> 6;          // 0..7
    const int wr = wid >> 1;           // 0..3 (M: 64-row quarter)
    const int wc = wid & 1;            // 0..1 (N: 64-col half)
    const int l0 = lane & 15, lh = lane >> 4;

    // chunked XCD swizzle (bijective: NWG % 8 == 0)
    const int h = blockIdx.x;
    const int l = (h & 7) * (NWG / 8) + (h >> 3);
    const int bn0 = (l & (GX - 1)) * 128;
    const int bm0 = (l / GX) * 256;

    float4v acc[4][4];
#pragma unroll
    for (int m = 0; m < 4; ++m)
#pragma unroll
        for (int n = 0; n < 4; ++n) acc[m][n] = (float4v){0.f, 0.f, 0.f, 0.f};

    // staging: A 2 instrs (1024 slots), B 1 instr (512 slots); 3 loads/thread
    // slot flat: row r = flat>>2 (4 chunks/row), cc = flat&3;
    // source chunk = cc ^ ((r>>1)&3) within the row's 64B span (coalesced)
    int growA[2], gchA[2], growB, gchB;
#pragma unroll
    for (int i = 0; i < 2; ++i) {
        int flat = i * 512 + tid;
        growA[i] = flat >> 2;
        gchA[i] = (((flat & 3) ^ ((growA[i] >> 1) & 3))) * 8;
    }
    growB = tid >> 2;
    gchB = (((tid & 3) ^ ((growB >> 1) & 3))) * 8;

#define STAGE(buf, kt)                                                        \
    {                                                                         \
        const int k0 = (kt) * BK;                                             \
        _Pragma("unroll") for (int i = 0; i < 2; ++i)                         \
            gl2lds16(&A[(size_t)(bm0 + growA[i]) * K + k0 + gchA[i]],         \
                     &lsA[buf][(i * 512 + tid) * 8]);                         \
        gl2lds16(&Bt[(size_t)(bn0 + growB) * K + k0 + gchB],                  \
                 &lsB[buf][tid * 8]);                                         \
    }

    // prologue: 2 tiles in flight (6 loads/thread outstanding)
    STAGE(0, 0);
    STAGE(1, 1);

    for (int kt = 0; kt < NKT; ++kt) {
        const int cur = kt % 3;
        // wait only for the OLDEST tile's 3 loads; keep the next 3 in flight
        if (kt + 1 < NKT)
            asm volatile("s_waitcnt vmcnt(3)" ::: "memory");
        else
            asm volatile("s_waitcnt vmcnt(0)" ::: "memory");
        __builtin_amdgcn_s_barrier();
        __builtin_amdgcn_sched_barrier(0);
        // prefetch tile kt+2 into the buffer last read at iter kt-1 (safe:
        // those reads completed at iter kt-1's lgkmcnt(0), before barrier kt)
        if (kt + 2 < NKT) STAGE((kt + 2) % 3, kt + 2);
        short8 af[4], bf[4];
#pragma unroll
        for (int m = 0; m < 4; ++m) {
            int r = wr * 64 + m * 16 + l0;
            af[m] = *(const short8*)&lsA[cur][r * 32 + ((lh ^ ((r >> 1) & 3)) * 8)];
        }
#pragma unroll
        for (int n = 0; n < 4; ++n) {
            int r = wc * 64 + n * 16 + l0;
            bf[n] = *(const short8*)&lsB[cur][r * 32 + ((lh ^ ((r >> 1) & 3)) * 8)];
        }
        asm volatile("s_waitcnt lgkmcnt(0)" ::: "memory");
        __builtin_amdgcn_sched_barrier(0);
        __builtin_amdgcn_s_setprio(1);
#pragma unroll
        for (int m = 0; m < 4; ++m)
#pragma unroll
            for (int n = 0; n < 4; ++n)
                acc[m][n] = __builtin_amdgcn_mfma_f32_16x16x32_bf16(
                    af[m], bf[n], acc[m][n], 0, 0, 0);
        __builtin_amdgcn_s_setprio(0);
    }
#undef STAGE

#pragma unroll
    for (int m = 0; m < 4; ++m) {
#pragma unroll
        for (int n = 0; n < 4; ++n) {
            int col = bn0 + wc * 64 + n * 16 + l0;
            float bv = bias[col];
#pragma unroll
            for (int r = 0; r < 4; ++r) {
                int rw = bm0 + wr * 64 + m * 16 + lh * 4 + r;
                float u = acc[m][n][r] + bv;
                size_t oidx = (size_t)rw * 512 + (col & 511);
                if (MODE == 1) {
                    if (col < 512)
                        ((u16*)o0v)[oidx] = f2b(tanh_fast(u));
                    else
                        ((u16*)o1v)[oidx] = f2b(sigm(u));
                } else if (MODE == 2) {
                    int e = col >> 9;
                    if (e == 0)
                        ((u16*)o0v)[oidx] = f2b(sigm(u));
                    else if (e == 1)
                        ((u16*)o1v)[oidx] = f2b(sigm(u));
                    else if (e == 2)
                        ((u16*)o2v)[oidx] = f2b(sigm(u));
                    else
                        ((u16*)o3v)[oidx] = f2b(tanh_fast(u));
                } else {
                    ((float*)o0v)[oidx] = u;
                }
            }
        }
    }
}

// ---------------- chunked scan (bf16 streams, f32 state) ----------------
template <int S>
__global__ __launch_bounds__(128) void scan_p1(const u16* __restrict__ f,
                                               const u16* __restrict__ v,
                                               const u16* __restrict__ z,
                                               float* __restrict__ cA,
                                               float* __restrict__ cB) {
    int d0 = threadIdx.x * 4;
    int c = blockIdx.x & (NC - 1);
    int b = blockIdx.x >> 7;
    size_t base = ((size_t)b * T_LEN + c * CH) * DDIM + d0;
    float Aa[4] = {1.f, 1.f, 1.f, 1.f}, Bb[4] = {0.f, 0.f, 0.f, 0.f};
    for (int t = 0; t < CH; ++t) {
        ushort4 fq = *(const ushort4*)&f[base];
        ushort4 vq = *(const ushort4*)&v[base];
        float ff[4] = {b2f(fq.x), b2f(fq.y), b2f(fq.z), b2f(fq.w)};
        float gg[4] = {b2f(vq.x), b2f(vq.y), b2f(vq.z), b2f(vq.w)};
        if (S == 2) {
            ushort4 zq = *(const ushort4*)&z[base];
            gg[0] *= b2f(zq.x); gg[1] *= b2f(zq.y);
            gg[2] *= b2f(zq.z); gg[3] *= b2f(zq.w);
        }
#pragma unroll
        for (int j = 0; j < 4; ++j) {
            float g = (1.f - ff[j]) * gg[j];
            Bb[j] = ff[j] * Bb[j] + g;
            Aa[j] *= ff[j];
        }
        base += DDIM;
    }
    size_t ci = (size_t)c * 4096 + b * DDIM + d0;
#pragma unroll
    for (int j = 0; j < 4; ++j) {
        cA[ci + j] = Aa[j];
        cB[ci + j] = Bb[j];
    }
}

__global__ __launch_bounds__(256) void scan_p2(float* __restrict__ cA,
                                               const float* __restrict__ cB) {
    int ln = blockIdx.x * 256 + threadIdx.x;  // 0..4095 = b*512+d
    float h = 0.f;
    for (int c = 0; c < NC; ++c) {
        size_t ix = (size_t)c * 4096 + ln;
        float a = cA[ix], bb = cB[ix];
        cA[ix] = h;  // exclusive carry-in
        h = a * h + bb;
    }
}

template <int S>
__global__ __launch_bounds__(128) void scan_p3(
    const u16* __restrict__ f, const u16* __restrict__ v,
    const u16* __restrict__ z, const u16* __restrict__ o,
    const float* __restrict__ cA, u16* __restrict__ hb,
    float* __restrict__ hid) {
    int d0 = threadIdx.x * 4;
    int c = blockIdx.x & (NC - 1);
    int b = blockIdx.x >> 7;
    size_t base = ((size_t)b * T_LEN + c * CH) * DDIM + d0;
    size_t ci = (size_t)c * 4096 + b * DDIM + d0;
    float h[4] = {cA[ci], cA[ci + 1], cA[ci + 2], cA[ci + 3]};
    for (int t = 0; t < CH; ++t) {
        ushort4 fq = *(const ushort4*)&f[base];
        ushort4 vq = *(const ushort4*)&v[base];
        float ff[4] = {b2f(fq.x), b2f(fq.y), b2f(fq.z), b2f(fq.w)};
        float gg[4] = {b2f(vq.x), b2f(vq.y), b2f(vq.z), b2f(vq.w)};
        if (S == 2) {
            ushort4 zq = *(const ushort4*)&z[base];
            gg[0] *= b2f(zq.x); gg[1] *= b2f(zq.y);
            gg[2] *= b2f(zq.z); gg[3] *= b2f(zq.w);
        }
        float w[4];
#pragma unroll
        for (int j = 0; j < 4; ++j) {
            float g = (1.f - ff[j]) * gg[j];
            h[j] = ff[j] * h[j] + g;
            w[j] = h[j];
        }
        if (S == 2) {
            ushort4 oq = *(const ushort4*)&o[base];
            w[0] *= b2f(oq.x); w[1] *= b2f(oq.y);
            w[2] *= b2f(oq.z); w[3] *= b2f(oq.w);
        }
        ushort4 p;
        p.x = f2b(w[0]); p.y = f2b(w[1]); p.z = f2b(w[2]); p.w = f2b(w[3]);
        *(ushort4*)&hb[base] = p;
        base += DDIM;
    }
    if (c == NC - 1) {
#pragma unroll
        for (int j = 0; j < 4; ++j)
            hid[b * 1024 + (S == 1 ? 0 : 512) + d0 + j] = h[j];
    }
}

// ---------------- launch ----------------
extern "C" void kernel_launch(void* const* d_in, const int* in_sizes, int n_in,
                              void* d_out, int out_size, void* d_ws,
                              size_t ws_size, hipStream_t stream) {
    const float* x = (const float*)d_in[0];
    const float* W_in = (const float*)d_in[1];
    const float* b_in = (const float*)d_in[2];
    const float* W_mid = (const float*)d_in[3];
    const float* b_mid = (const float*)d_in[4];
    const float* W_out = (const float*)d_in[5];
    const float* b_out = (const float*)d_in[6];
    float* out = (float*)d_out;
    char* ws = (char*)d_ws;

    const size_t MB = 1u << 20;
    const size_t MD = (size_t)MROWS * DDIM;  // 16.7M elems

    u16* wt_in = (u16*)(ws);              // 1 MB
    u16* wt_mid = (u16*)(ws + 1 * MB);    // 2 MB
    u16* wt_out = (u16*)(ws + 3 * MB);    // 0.5 MB
    u16* hb = (u16*)(ws + 4 * MB);        // 32 MB (xb -> h1 -> s)
    u16* S0 = (u16*)(ws + 36 * MB);       // 32 MB
    u16* S1 = (u16*)(ws + 68 * MB);       // 32 MB
    u16* S2 = (u16*)(ws + 100 * MB);      // 32 MB
    u16* S3 = (u16*)(ws + 132 * MB);      // 32 MB
    float* cA = (float*)(ws + 164 * MB);  // 2 MB
    float* cB = (float*)(ws + 166 * MB);  // 2 MB
    float* hid = out + MD;

    cvt_x<<<(int)(MD / 4 / 256), 256, 0, stream>>>(x, hb, MD);
    cvt_wt<<<(1024 * 512) / 256, 256, 0, stream>>>(W_in, wt_in, 1024);
    cvt_wt<<<(2048 * 512) / 256, 256, 0, stream>>>(W_mid, wt_mid, 2048);
    cvt_wt<<<(512 * 512) / 256, 256, 0, stream>>>(W_out, wt_out, 512);

    // GEMM1: v(S0)=tanh, f1(S1)=sigmoid   (128 Mblk x 8 Nblk = 1024)
    gemm_act<1><<<1024, 512, 0, stream>>>(hb, wt_in, b_in, S0, S1, nullptr,
                                          nullptr);
    // scan1: h1 = scan(f1, (1-f1)*v) -> hb bf16; hidden_pre
    scan_p1<1><<<1024, 128, 0, stream>>>(S1, S0, nullptr, cA, cB);
    scan_p2<<<16, 256, 0, stream>>>(cA, cB);
    scan_p3<1><<<1024, 128, 0, stream>>>(S1, S0, nullptr, nullptr, cA, hb, hid);

    // GEMM2: f2(S0), i(S1), o(S2), z(S3)  (128 x 16 = 2048)
    gemm_act<2><<<2048, 512, 0, stream>>>(hb, wt_mid, b_mid, S0, S1, S2, S3);
    // scan2: h2 = scan(f2, (1-f2)*i*z); s = h2*o -> hb bf16; hidden_middle
    scan_p1<2><<<1024, 128, 0, stream>>>(S0, S1, S3, cA, cB);
    scan_p2<<<16, 256, 0, stream>>>(cA, cB);
    scan_p3<2><<<1024, 128, 0, stream>>>(S0, S1, S3, S2, cA, hb, hid);

    // GEMM3: out = s@W_out + b_out (f32)  (128 x 4 = 512)
    gemm_act<3><<<512, 512, 0, stream>>>(hb, wt_out, b_out, out, nullptr,
                                         nullptr, nullptr);
}